// Round 1
// baseline (45640.735 us; speedup 1.0000x reference)
//
#include <hip/hip_runtime.h>
#include <math.h>

#define T_LEN 8000
#define BATCH 2
#define RES 512
#define SKP 256
#define AUX 28
#define NQ 256
#define NLAYER 30
#define NTT 125            // T tiles of 64
#define LDSTRIDE 68        // padded LDS row stride (floats): 2-way bank alias only

// ---------------- zero skip_sum ----------------
__global__ __launch_bounds__(256) void zero_f4(float4* p, int n4) {
  int i = blockIdx.x * 256 + threadIdx.x;
  int stride = gridDim.x * 256;
  for (; i < n4; i += stride) p[i] = make_float4(0.f, 0.f, 0.f, 0.f);
}

// ---------------- embed: one-hot causal conv == table lookup ----------------
// out[b,o,t] = cb[o] + cw[o, x[t], 1] + (t>=1 ? cw[o, x[t-1], 0] : 0)
__global__ __launch_bounds__(256) void embed_kernel(
    const int* __restrict__ x, const float* __restrict__ cw,
    const float* __restrict__ cb, float* __restrict__ out) {
  int b = blockIdx.z;
  int o0 = blockIdx.y * 64;
  int t0 = blockIdx.x * 64;
  __shared__ int xs[65];
  int tid = threadIdx.x;
  if (tid < 65) {
    int t = t0 + tid - 1;
    xs[tid] = (t >= 0) ? (x[b * T_LEN + t] & 255) : 0;
  }
  __syncthreads();
  int tn = tid & 63, oo = tid >> 6;
  int t = t0 + tn;
  int xc = xs[tn + 1], xp = xs[tn];
  float won = (t >= 1) ? 1.f : 0.f;
  for (int j = 0; j < 16; ++j) {
    int o = o0 + j * 4 + oo;
    float w1 = cw[(o * NQ + xc) * 2 + 1];
    float w0 = cw[(o * NQ + xp) * 2 + 0];
    out[(b * RES + o) * T_LEN + t] = cb[o] + w1 + won * w0;
  }
}

// ---------------- gate: z = sigmoid(sig) * tanh(tan) ----------------
// sig[b,o,t] = sum_i Ws0[o,i]*prev[b,i,t-d] + Ws1[o,i]*prev[b,i,t]
//            + sum_j As[o,j]*h[b,j,t] + bsig1[o] + bsig2[o]
__global__ __launch_bounds__(256) void gate_kernel(
    const float* __restrict__ prev, const float* __restrict__ h,
    const float* __restrict__ wsig, const float* __restrict__ wtan,
    const float* __restrict__ asig, const float* __restrict__ atanw,
    const float* __restrict__ bsig1, const float* __restrict__ bsig2,
    const float* __restrict__ btan1, const float* __restrict__ btan2,
    float* __restrict__ z, int d) {
  __shared__ __align__(16) float sm[6 * 16 * LDSTRIDE];
  float (*a_s0)[LDSTRIDE] = (float(*)[LDSTRIDE])(sm + 0 * 16 * LDSTRIDE);
  float (*a_s1)[LDSTRIDE] = (float(*)[LDSTRIDE])(sm + 1 * 16 * LDSTRIDE);
  float (*a_t0)[LDSTRIDE] = (float(*)[LDSTRIDE])(sm + 2 * 16 * LDSTRIDE);
  float (*a_t1)[LDSTRIDE] = (float(*)[LDSTRIDE])(sm + 3 * 16 * LDSTRIDE);
  float (*b_c)[LDSTRIDE]  = (float(*)[LDSTRIDE])(sm + 4 * 16 * LDSTRIDE);
  float (*b_p)[LDSTRIDE]  = (float(*)[LDSTRIDE])(sm + 5 * 16 * LDSTRIDE);

  int tid = threadIdx.x;
  int bt = blockIdx.x;
  int b = bt / NTT;
  int t0 = (bt % NTT) * 64;
  int o0 = blockIdx.y * 64;
  const float* pb = prev + (size_t)b * RES * T_LEN;

  int mrow = (tid >> 4) << 2;
  int ncol = (tid & 15) << 2;

  float sacc[4][4] = {{0.f}};
  float tacc[4][4] = {{0.f}};

  for (int k0 = 0; k0 < RES; k0 += 16) {
#pragma unroll
    for (int j = 0; j < 4; ++j) {
      int idx = tid + j * 256;
      int o = idx >> 4, i = idx & 15;
      float2 w2s = *(const float2*)&wsig[((o0 + o) * RES + (k0 + i)) * 2];
      float2 w2t = *(const float2*)&wtan[((o0 + o) * RES + (k0 + i)) * 2];
      a_s0[i][o] = w2s.x; a_s1[i][o] = w2s.y;
      a_t0[i][o] = w2t.x; a_t1[i][o] = w2t.y;
    }
#pragma unroll
    for (int j = 0; j < 4; ++j) {
      int idx = tid + j * 256;
      int i = idx >> 6, n = idx & 63;
      int t = t0 + n;
      b_c[i][n] = pb[(k0 + i) * T_LEN + t];
      int tp = t - d;
      b_p[i][n] = (tp >= 0) ? pb[(k0 + i) * T_LEN + tp] : 0.f;
    }
    __syncthreads();
#pragma unroll
    for (int kk = 0; kk < 16; ++kk) {
      float4 vs0 = *(const float4*)&a_s0[kk][mrow];
      float4 vs1 = *(const float4*)&a_s1[kk][mrow];
      float4 vt0 = *(const float4*)&a_t0[kk][mrow];
      float4 vt1 = *(const float4*)&a_t1[kk][mrow];
      float4 vxc = *(const float4*)&b_c[kk][ncol];
      float4 vxp = *(const float4*)&b_p[kk][ncol];
      float s0[4] = {vs0.x, vs0.y, vs0.z, vs0.w};
      float s1[4] = {vs1.x, vs1.y, vs1.z, vs1.w};
      float q0[4] = {vt0.x, vt0.y, vt0.z, vt0.w};
      float q1[4] = {vt1.x, vt1.y, vt1.z, vt1.w};
      float xc[4] = {vxc.x, vxc.y, vxc.z, vxc.w};
      float xp[4] = {vxp.x, vxp.y, vxp.z, vxp.w};
#pragma unroll
      for (int m = 0; m < 4; ++m)
#pragma unroll
        for (int n = 0; n < 4; ++n) {
          sacc[m][n] += s0[m] * xp[n] + s1[m] * xc[n];
          tacc[m][n] += q0[m] * xp[n] + q1[m] * xc[n];
        }
    }
    __syncthreads();
  }

  // aux phase: reuse LDS (28xK tiles)
  float (*h_s)[LDSTRIDE]  = (float(*)[LDSTRIDE])(sm + 0);
  float (*wa_s)[LDSTRIDE] = (float(*)[LDSTRIDE])(sm + 2 * 16 * LDSTRIDE);
  float (*wa_t)[LDSTRIDE] = (float(*)[LDSTRIDE])(sm + 4 * 16 * LDSTRIDE);
  for (int idx = tid; idx < AUX * 64; idx += 256) {
    int j = idx >> 6, n = idx & 63;
    h_s[j][n] = h[((size_t)b * AUX + j) * T_LEN + t0 + n];
  }
  for (int idx = tid; idx < 64 * AUX; idx += 256) {
    int o = idx / AUX, j = idx % AUX;
    wa_s[j][o] = asig[(o0 + o) * AUX + j];
    wa_t[j][o] = atanw[(o0 + o) * AUX + j];
  }
  __syncthreads();
#pragma unroll 4
  for (int j = 0; j < AUX; ++j) {
    float4 vas = *(const float4*)&wa_s[j][mrow];
    float4 vat = *(const float4*)&wa_t[j][mrow];
    float4 vh  = *(const float4*)&h_s[j][ncol];
    float as[4] = {vas.x, vas.y, vas.z, vas.w};
    float at[4] = {vat.x, vat.y, vat.z, vat.w};
    float hv[4] = {vh.x, vh.y, vh.z, vh.w};
#pragma unroll
    for (int m = 0; m < 4; ++m)
#pragma unroll
      for (int n = 0; n < 4; ++n) {
        sacc[m][n] += as[m] * hv[n];
        tacc[m][n] += at[m] * hv[n];
      }
  }

#pragma unroll
  for (int m = 0; m < 4; ++m) {
    int o = o0 + mrow + m;
    float bs = bsig1[o] + bsig2[o];
    float bt2 = btan1[o] + btan2[o];
    float4 zv;
    float s, tt;
    s = sacc[m][0] + bs; tt = tacc[m][0] + bt2;
    zv.x = (1.f / (1.f + expf(-s))) * tanhf(tt);
    s = sacc[m][1] + bs; tt = tacc[m][1] + bt2;
    zv.y = (1.f / (1.f + expf(-s))) * tanhf(tt);
    s = sacc[m][2] + bs; tt = tacc[m][2] + bt2;
    zv.z = (1.f / (1.f + expf(-s))) * tanhf(tt);
    s = sacc[m][3] + bs; tt = tacc[m][3] + bt2;
    zv.w = (1.f / (1.f + expf(-s))) * tanhf(tt);
    *(float4*)(z + ((size_t)b * RES + o) * T_LEN + t0 + ncol) = zv;
  }
}

// ---------------- update: skip_sum += Sk@z + skip_b ; out += Rw@z + res_b ----
// stacked rows: [0,256) -> skip, [256,768) -> res
__global__ __launch_bounds__(256) void update_kernel(
    const float* __restrict__ z,
    const float* __restrict__ skip_w, const float* __restrict__ skip_b,
    const float* __restrict__ res_w, const float* __restrict__ res_b,
    float* __restrict__ skip_sum, float* __restrict__ out) {
  __shared__ __align__(16) float sm[2 * 16 * LDSTRIDE];
  float (*a_s)[LDSTRIDE] = (float(*)[LDSTRIDE])(sm);
  float (*b_s)[LDSTRIDE] = (float(*)[LDSTRIDE])(sm + 16 * LDSTRIDE);
  int tid = threadIdx.x;
  int bt = blockIdx.x;
  int b = bt / NTT;
  int t0 = (bt % NTT) * 64;
  int r0 = blockIdx.y * 64;
  bool is_skip = (r0 < SKP);
  const float* w = is_skip ? (skip_w + (size_t)r0 * RES)
                           : (res_w + (size_t)(r0 - SKP) * RES);
  const float* zb = z + (size_t)b * RES * T_LEN;
  int mrow = (tid >> 4) << 2;
  int ncol = (tid & 15) << 2;
  float acc[4][4] = {{0.f}};
  for (int k0 = 0; k0 < RES; k0 += 16) {
#pragma unroll
    for (int j = 0; j < 4; ++j) {
      int idx = tid + j * 256;
      int o = idx >> 4, i = idx & 15;
      a_s[i][o] = w[o * RES + k0 + i];
    }
#pragma unroll
    for (int j = 0; j < 4; ++j) {
      int idx = tid + j * 256;
      int i = idx >> 6, n = idx & 63;
      b_s[i][n] = zb[(k0 + i) * T_LEN + t0 + n];
    }
    __syncthreads();
#pragma unroll
    for (int kk = 0; kk < 16; ++kk) {
      float4 va = *(const float4*)&a_s[kk][mrow];
      float4 vb = *(const float4*)&b_s[kk][ncol];
      float av[4] = {va.x, va.y, va.z, va.w};
      float bv[4] = {vb.x, vb.y, vb.z, vb.w};
#pragma unroll
      for (int m = 0; m < 4; ++m)
#pragma unroll
        for (int n = 0; n < 4; ++n) acc[m][n] += av[m] * bv[n];
    }
    __syncthreads();
  }
  if (is_skip) {
#pragma unroll
    for (int m = 0; m < 4; ++m) {
      int rr = r0 + mrow + m;
      float bias = skip_b[rr];
      float4* p = (float4*)(skip_sum + ((size_t)b * SKP + rr) * T_LEN + t0 + ncol);
      float4 v = *p;
      v.x += acc[m][0] + bias; v.y += acc[m][1] + bias;
      v.z += acc[m][2] + bias; v.w += acc[m][3] + bias;
      *p = v;
    }
  } else {
#pragma unroll
    for (int m = 0; m < 4; ++m) {
      int rr = r0 - SKP + mrow + m;
      float bias = res_b[rr];
      float4* p = (float4*)(out + ((size_t)b * RES + rr) * T_LEN + t0 + ncol);
      float4 v = *p;
      v.x += acc[m][0] + bias; v.y += acc[m][1] + bias;
      v.z += acc[m][2] + bias; v.w += acc[m][3] + bias;
      *p = v;
    }
  }
}

// ---------------- post1: y1 = relu(W1 @ relu(skip_sum) + b1) ----------------
__global__ __launch_bounds__(256) void post1_kernel(
    const float* __restrict__ skip_sum, const float* __restrict__ w,
    const float* __restrict__ bias, float* __restrict__ y1) {
  __shared__ __align__(16) float sm[2 * 16 * LDSTRIDE];
  float (*a_s)[LDSTRIDE] = (float(*)[LDSTRIDE])(sm);
  float (*b_s)[LDSTRIDE] = (float(*)[LDSTRIDE])(sm + 16 * LDSTRIDE);
  int tid = threadIdx.x;
  int bt = blockIdx.x;
  int b = bt / NTT;
  int t0 = (bt % NTT) * 64;
  int r0 = blockIdx.y * 64;
  int mrow = (tid >> 4) << 2;
  int ncol = (tid & 15) << 2;
  float acc[4][4] = {{0.f}};
  for (int k0 = 0; k0 < SKP; k0 += 16) {
#pragma unroll
    for (int j = 0; j < 4; ++j) {
      int idx = tid + j * 256;
      int o = idx >> 4, i = idx & 15;
      a_s[i][o] = w[(r0 + o) * SKP + k0 + i];
    }
#pragma unroll
    for (int j = 0; j < 4; ++j) {
      int idx = tid + j * 256;
      int i = idx >> 6, n = idx & 63;
      float v = skip_sum[((size_t)b * SKP + k0 + i) * T_LEN + t0 + n];
      b_s[i][n] = fmaxf(v, 0.f);
    }
    __syncthreads();
#pragma unroll
    for (int kk = 0; kk < 16; ++kk) {
      float4 va = *(const float4*)&a_s[kk][mrow];
      float4 vb = *(const float4*)&b_s[kk][ncol];
      float av[4] = {va.x, va.y, va.z, va.w};
      float bv[4] = {vb.x, vb.y, vb.z, vb.w};
#pragma unroll
      for (int m = 0; m < 4; ++m)
#pragma unroll
        for (int n = 0; n < 4; ++n) acc[m][n] += av[m] * bv[n];
    }
    __syncthreads();
  }
#pragma unroll
  for (int m = 0; m < 4; ++m) {
    int rr = r0 + mrow + m;
    float bb = bias[rr];
    float4 v;
    v.x = fmaxf(acc[m][0] + bb, 0.f);
    v.y = fmaxf(acc[m][1] + bb, 0.f);
    v.z = fmaxf(acc[m][2] + bb, 0.f);
    v.w = fmaxf(acc[m][3] + bb, 0.f);
    *(float4*)(y1 + ((size_t)b * SKP + rr) * T_LEN + t0 + ncol) = v;
  }
}

// ---------------- post2: out[b,t,q] = W2 @ y1 + b2 (transposed store) -------
__global__ __launch_bounds__(256) void post2_kernel(
    const float* __restrict__ y1, const float* __restrict__ w,
    const float* __restrict__ bias, float* __restrict__ outp) {
  __shared__ __align__(16) float sm[2 * 16 * LDSTRIDE];
  float (*a_s)[LDSTRIDE] = (float(*)[LDSTRIDE])(sm);
  float (*b_s)[LDSTRIDE] = (float(*)[LDSTRIDE])(sm + 16 * LDSTRIDE);
  int tid = threadIdx.x;
  int bt = blockIdx.x;
  int b = bt / NTT;
  int t0 = (bt % NTT) * 64;
  int r0 = blockIdx.y * 64;
  int mrow = (tid >> 4) << 2;
  int ncol = (tid & 15) << 2;
  float acc[4][4] = {{0.f}};
  for (int k0 = 0; k0 < SKP; k0 += 16) {
#pragma unroll
    for (int j = 0; j < 4; ++j) {
      int idx = tid + j * 256;
      int o = idx >> 4, i = idx & 15;
      a_s[i][o] = w[(r0 + o) * SKP + k0 + i];
    }
#pragma unroll
    for (int j = 0; j < 4; ++j) {
      int idx = tid + j * 256;
      int i = idx >> 6, n = idx & 63;
      b_s[i][n] = y1[((size_t)b * SKP + k0 + i) * T_LEN + t0 + n];
    }
    __syncthreads();
#pragma unroll
    for (int kk = 0; kk < 16; ++kk) {
      float4 va = *(const float4*)&a_s[kk][mrow];
      float4 vb = *(const float4*)&b_s[kk][ncol];
      float av[4] = {va.x, va.y, va.z, va.w};
      float bv[4] = {vb.x, vb.y, vb.z, vb.w};
#pragma unroll
      for (int m = 0; m < 4; ++m)
#pragma unroll
        for (int n = 0; n < 4; ++n) acc[m][n] += av[m] * bv[n];
    }
    __syncthreads();
  }
#pragma unroll
  for (int n = 0; n < 4; ++n) {
    int t = t0 + ncol + n;
    float4 v;
    v.x = acc[0][n] + bias[r0 + mrow + 0];
    v.y = acc[1][n] + bias[r0 + mrow + 1];
    v.z = acc[2][n] + bias[r0 + mrow + 2];
    v.w = acc[3][n] + bias[r0 + mrow + 3];
    *(float4*)(outp + ((size_t)(b * T_LEN + t)) * NQ + r0 + mrow) = v;
  }
}

extern "C" void kernel_launch(void* const* d_in, const int* in_sizes, int n_in,
                              void* d_out, int out_size, void* d_ws, size_t ws_size,
                              hipStream_t stream) {
  const int*   x          = (const int*)d_in[0];
  const float* h          = (const float*)d_in[1];
  const float* causal_w   = (const float*)d_in[2];
  const float* causal_b   = (const float*)d_in[3];
  const float* dil_sig_w  = (const float*)d_in[4];
  const float* dil_sig_b  = (const float*)d_in[5];
  const float* dil_tanh_w = (const float*)d_in[6];
  const float* dil_tanh_b = (const float*)d_in[7];
  const float* aux_sig_w  = (const float*)d_in[8];
  const float* aux_sig_b  = (const float*)d_in[9];
  const float* aux_tanh_w = (const float*)d_in[10];
  const float* aux_tanh_b = (const float*)d_in[11];
  const float* skip_w     = (const float*)d_in[12];
  const float* skip_b     = (const float*)d_in[13];
  const float* res_w      = (const float*)d_in[14];
  const float* res_b      = (const float*)d_in[15];
  const float* post1_w    = (const float*)d_in[16];
  const float* post1_b    = (const float*)d_in[17];
  const float* post2_w    = (const float*)d_in[18];
  const float* post2_b    = (const float*)d_in[19];
  float* outp = (float*)d_out;

  float* ws      = (float*)d_ws;
  float* outbuf  = ws;                       // 2*512*8000 floats
  float* zbuf    = ws + (size_t)BATCH * RES * T_LEN;      // 2*512*8000
  float* skipbuf = ws + (size_t)2 * BATCH * RES * T_LEN;  // 2*256*8000
  float* y1buf   = zbuf;  // reuse after layers are done

  zero_f4<<<1024, 256, 0, stream>>>((float4*)skipbuf,
                                    (BATCH * SKP * T_LEN) / 4);
  embed_kernel<<<dim3(NTT, RES / 64, BATCH), 256, 0, stream>>>(
      x, causal_w, causal_b, outbuf);

  for (int l = 0; l < NLAYER; ++l) {
    int d = 1 << (l % 10);
    gate_kernel<<<dim3(NTT * BATCH, RES / 64), 256, 0, stream>>>(
        outbuf, h,
        dil_sig_w + (size_t)l * RES * RES * 2,
        dil_tanh_w + (size_t)l * RES * RES * 2,
        aux_sig_w + (size_t)l * RES * AUX,
        aux_tanh_w + (size_t)l * RES * AUX,
        dil_sig_b + (size_t)l * RES, aux_sig_b + (size_t)l * RES,
        dil_tanh_b + (size_t)l * RES, aux_tanh_b + (size_t)l * RES,
        zbuf, d);
    update_kernel<<<dim3(NTT * BATCH, (SKP + RES) / 64), 256, 0, stream>>>(
        zbuf,
        skip_w + (size_t)l * SKP * RES, skip_b + (size_t)l * SKP,
        res_w + (size_t)l * RES * RES, res_b + (size_t)l * RES,
        skipbuf, outbuf);
  }

  post1_kernel<<<dim3(NTT * BATCH, SKP / 64), 256, 0, stream>>>(
      skipbuf, post1_w, post1_b, y1buf);
  post2_kernel<<<dim3(NTT * BATCH, NQ / 64), 256, 0, stream>>>(
      y1buf, post2_w, post2_b, outp);
}

// Round 3
// 3902.965 us; speedup vs baseline: 11.6939x; 11.6939x over previous
//
#include <hip/hip_runtime.h>
#include <math.h>

#define T_LEN 8000
#define BATCH 2
#define CCH 512
#define SKP 256
#define AUXP 32
#define NQ 256
#define NLAYER 30
#define PADF 512
#define ROWS (PADF + T_LEN + 64)   // 8576 padded rows (fp32 master / fp16 copy)
#define HROWS (T_LEN + 64)         // 8064 rows (z, h, y1)
#define BM 128
#define BN 128
#define NTT 63                     // ceil(8000/128)

typedef unsigned short hfu;        // fp16 as raw bits
typedef unsigned int u32;
typedef __attribute__((ext_vector_type(8))) _Float16 half8;
typedef __attribute__((ext_vector_type(4))) float f32x4;

#define GLOAD16(g, l)                                                          \
  __builtin_amdgcn_global_load_lds(                                            \
      (const __attribute__((address_space(1))) void*)(g),                      \
      (__attribute__((address_space(3))) void*)(l), 16, 0, 0)

__device__ inline hfu hfbits(float f) {
  union { _Float16 h; hfu u; } x;
  x.h = (_Float16)f;
  return x.u;
}
__device__ inline u32 pk2(float a, float b) {
  return (u32)hfbits(a) | ((u32)hfbits(b) << 16);
}
__device__ inline uint4 pk8(const float f[8]) {
  return make_uint4(pk2(f[0], f[1]), pk2(f[2], f[3]), pk2(f[4], f[5]), pk2(f[6], f[7]));
}

// ---------------- utility: zero / converts ----------------
__global__ __launch_bounds__(256) void zero16(uint4* p, int n) {
  for (int i = blockIdx.x * 256 + threadIdx.x; i < n; i += gridDim.x * 256)
    p[i] = make_uint4(0u, 0u, 0u, 0u);
}

// dil weights: in [30][512][512][2] f32 -> out [30][2][512][512] fp16 (tap-deinterleaved)
__global__ __launch_bounds__(256) void cvt_dil(const float* __restrict__ in, hfu* __restrict__ out) {
  const long NG = (long)NLAYER * CCH * (CCH / 4);
  for (long g = (long)blockIdx.x * 256 + threadIdx.x; g < NG; g += (long)gridDim.x * 256) {
    const int i4 = (int)(g & 127) * 4;
    const int o = (int)((g >> 7) & 511);
    const int l = (int)(g >> 16);
    const float* pp = in + (((size_t)l * CCH + o) * CCH + i4) * 2;
    float4 f0 = *(const float4*)pp;
    float4 f1 = *(const float4*)(pp + 4);
    uint2 t0 = make_uint2(pk2(f0.x, f0.z), pk2(f1.x, f1.z));
    uint2 t1 = make_uint2(pk2(f0.y, f0.w), pk2(f1.y, f1.w));
    hfu* ob = out + ((size_t)l * 2 * CCH + o) * CCH + i4;
    *(uint2*)ob = t0;
    *(uint2*)(ob + (size_t)CCH * CCH) = t1;
  }
}

// skip_w [30][256][512] + res_w [30][512][512] -> stacked [30][768][512] fp16
__global__ __launch_bounds__(256) void cvt_skipres(const float* __restrict__ skw,
                                                   const float* __restrict__ rsw,
                                                   hfu* __restrict__ out) {
  const long NG = (long)NLAYER * 768 * (CCH / 4);
  for (long g = (long)blockIdx.x * 256 + threadIdx.x; g < NG; g += (long)gridDim.x * 256) {
    const int i4 = (int)(g & 127) * 4;
    const int r = (int)((g >> 7) % 768);
    const int l = (int)(g / (128 * 768));
    const float* src = (r < SKP) ? (skw + ((size_t)l * SKP + r) * CCH + i4)
                                 : (rsw + ((size_t)l * CCH + (r - SKP)) * CCH + i4);
    float4 f = *(const float4*)src;
    *(uint2*)(out + ((size_t)l * 768 + r) * CCH + i4) = make_uint2(pk2(f.x, f.y), pk2(f.z, f.w));
  }
}

// aux weights [30][512][28] -> [30][512][32] fp16 zero-padded
__global__ __launch_bounds__(256) void cvt_aux(const float* __restrict__ in, hfu* __restrict__ out) {
  const int N = NLAYER * CCH * AUXP;
  for (int i = blockIdx.x * 256 + threadIdx.x; i < N; i += gridDim.x * 256) {
    const int j = i & 31;
    const int o = (i >> 5) & 511;
    const int l = i >> 14;
    float v = (j < 28) ? in[((size_t)l * CCH + o) * 28 + j] : 0.f;
    out[i] = hfbits(v);
  }
}

__global__ __launch_bounds__(256) void cvt_copy(const float* __restrict__ in, hfu* __restrict__ out, int n) {
  for (int i = blockIdx.x * 256 + threadIdx.x; i < n; i += gridDim.x * 256)
    out[i] = hfbits(in[i]);
}

// h [b][28][8000] f32 -> [b][8064][32] fp16 zero-padded
__global__ __launch_bounds__(256) void htrans_kernel(const float* __restrict__ h, hfu* __restrict__ hbf) {
  const int b = blockIdx.y;
  const int t = blockIdx.x * 64 + (threadIdx.x & 63);
  const int j0 = threadIdx.x >> 6;
#pragma unroll
  for (int j = j0; j < AUXP; j += 4) {
    float v = (j < 28 && t < T_LEN) ? h[((size_t)b * 28 + j) * T_LEN + t] : 0.f;
    hbf[((size_t)b * HROWS + t) * AUXP + j] = hfbits(v);
  }
}

// ---------------- embed ----------------
template <int PRE>
__global__ __launch_bounds__(256) void embed_kernel(const int* __restrict__ x,
                                                    const float* __restrict__ cw,
                                                    const float* __restrict__ cb,
                                                    float* __restrict__ outf,
                                                    hfu* __restrict__ outb) {
  const int b = blockIdx.y;
  const int t = blockIdx.x * 4 + (threadIdx.x >> 6);
  const int lane = threadIdx.x & 63;
  const int xc = x[(size_t)b * T_LEN + t] & 255;
  const int xp = (t > 0) ? (x[(size_t)b * T_LEN + t - 1] & 255) : 0;
#pragma unroll
  for (int j = 0; j < 8; ++j) {
    const int o = lane + j * 64;
    float v = cb[o] + cw[((size_t)o * NQ + xc) * 2 + 1];
    if (t > 0) v += cw[((size_t)o * NQ + xp) * 2];
    outf[((size_t)b * ROWS + PADF + t) * CCH + o] = v;
    if (PRE) outb[((size_t)b * ROWS + PADF + t) * CCH + o] = hfbits(v);
  }
}

// ---------------- gate: sig/tanh dilated GEMMs + aux + gating ----------------
template <int PRE>
__global__ __launch_bounds__(256, 2) void gate_kernel(
    const hfu* __restrict__ actb, const float* __restrict__ actf,
    const hfu* __restrict__ hbf,
    const void* __restrict__ wsp, const void* __restrict__ wtp,
    const hfu* __restrict__ auxs, const hfu* __restrict__ auxt,
    const float* __restrict__ bs1, const float* __restrict__ bs2,
    const float* __restrict__ bt1, const float* __restrict__ bt2,
    hfu* __restrict__ z, int d) {
  __shared__ uint4 sm[3072];  // 48KB: As | At | B, each [8 ksub][128][16B]
  uint4* sAs = sm;
  uint4* sAt = sm + 1024;
  uint4* sB = sm + 2048;
  const int tid = threadIdx.x;
  const int lane = tid & 63, wid = tid >> 6;
  const int wm = wid >> 1, wn = wid & 1;
  const int lr = lane & 15, lq = lane >> 4;
  const int t0 = blockIdx.x * BN;
  const int o0 = blockIdx.y * BM;
  const int b = blockIdx.z;

  f32x4 accS[4][4] = {};
  f32x4 accT[4][4] = {};

#pragma unroll
  for (int tau = 1; tau >= 0; --tau) {
    for (int it = 0; it < 8; ++it) {
      const int i0b = it * 64;
#pragma unroll
      for (int c = 0; c < 4; ++c) {
        const int cb = c * 256 + wid * 64;
        const int ch = cb + lane;
        const int ksub = ch >> 7, mn = ch & 127;
        const int i0 = i0b + ksub * 8;
        if (PRE) {
          const hfu* ws = (const hfu*)wsp + ((size_t)tau * CCH + o0 + mn) * CCH + i0;
          const hfu* wt = (const hfu*)wtp + ((size_t)tau * CCH + o0 + mn) * CCH + i0;
          GLOAD16(ws, &sAs[cb]);
          GLOAD16(wt, &sAt[cb]);
          const hfu* ar = actb + ((size_t)b * ROWS + PADF + t0 + mn - (tau ? 0 : d)) * CCH + i0;
          GLOAD16(ar, &sB[cb]);
        } else {
          const float* wsf = (const float*)wsp;
          const float* wtf = (const float*)wtp;
          const size_t fb = ((size_t)(o0 + mn) * CCH + i0) * 2;
          float vs[8], vt[8];
#pragma unroll
          for (int j = 0; j < 4; ++j) {
            float4 fs = *(const float4*)&wsf[fb + j * 4];
            float4 ft = *(const float4*)&wtf[fb + j * 4];
            vs[2 * j] = tau ? fs.y : fs.x;
            vs[2 * j + 1] = tau ? fs.w : fs.z;
            vt[2 * j] = tau ? ft.y : ft.x;
            vt[2 * j + 1] = tau ? ft.w : ft.z;
          }
          sAs[ch] = pk8(vs);
          sAt[ch] = pk8(vt);
          const float* ar = actf + ((size_t)b * ROWS + PADF + t0 + mn - (tau ? 0 : d)) * CCH + i0;
          float4 f0 = *(const float4*)&ar[0];
          float4 f1 = *(const float4*)&ar[4];
          float vb[8] = {f0.x, f0.y, f0.z, f0.w, f1.x, f1.y, f1.z, f1.w};
          sB[ch] = pk8(vb);
        }
      }
      __syncthreads();
#pragma unroll
      for (int ks = 0; ks < 2; ++ks) {
        const int kb = (ks * 4 + lq) * 128;
        half8 af[4], ag[4], bv[4];
#pragma unroll
        for (int r = 0; r < 4; ++r) {
          af[r] = *(const half8*)&sAs[kb + wm * 64 + r * 16 + lr];
          ag[r] = *(const half8*)&sAt[kb + wm * 64 + r * 16 + lr];
          bv[r] = *(const half8*)&sB[kb + wn * 64 + r * 16 + lr];
        }
#pragma unroll
        for (int mr = 0; mr < 4; ++mr)
#pragma unroll
          for (int nr = 0; nr < 4; ++nr) {
            accS[mr][nr] = __builtin_amdgcn_mfma_f32_16x16x32_f16(af[mr], bv[nr], accS[mr][nr], 0, 0, 0);
            accT[mr][nr] = __builtin_amdgcn_mfma_f32_16x16x32_f16(ag[mr], bv[nr], accT[mr][nr], 0, 0, 0);
          }
      }
      __syncthreads();
    }
  }

  // aux phase: K=32 (padded 28)
#pragma unroll
  for (int c = 0; c < 2; ++c) {
    const int cb = c * 256 + wid * 64;
    const int ch = cb + lane;
    const int ksub = ch >> 7, mn = ch & 127;
    GLOAD16(auxs + (size_t)(o0 + mn) * AUXP + ksub * 8, &sAs[cb]);
    GLOAD16(auxt + (size_t)(o0 + mn) * AUXP + ksub * 8, &sAt[cb]);
    GLOAD16(hbf + ((size_t)b * HROWS + t0 + mn) * AUXP + ksub * 8, &sB[cb]);
  }
  __syncthreads();
  {
    const int kb = lq * 128;
    half8 af[4], ag[4], bv[4];
#pragma unroll
    for (int r = 0; r < 4; ++r) {
      af[r] = *(const half8*)&sAs[kb + wm * 64 + r * 16 + lr];
      ag[r] = *(const half8*)&sAt[kb + wm * 64 + r * 16 + lr];
      bv[r] = *(const half8*)&sB[kb + wn * 64 + r * 16 + lr];
    }
#pragma unroll
    for (int mr = 0; mr < 4; ++mr)
#pragma unroll
      for (int nr = 0; nr < 4; ++nr) {
        accS[mr][nr] = __builtin_amdgcn_mfma_f32_16x16x32_f16(af[mr], bv[nr], accS[mr][nr], 0, 0, 0);
        accT[mr][nr] = __builtin_amdgcn_mfma_f32_16x16x32_f16(ag[mr], bv[nr], accT[mr][nr], 0, 0, 0);
      }
  }

  // epilogue: bias + sigmoid*tanh -> z fp16 [b][t][ch]
#pragma unroll
  for (int mr = 0; mr < 4; ++mr) {
    const int ob = o0 + wm * 64 + mr * 16 + lq * 4;
    float4 x1 = *(const float4*)&bs1[ob];
    float4 x2 = *(const float4*)&bs2[ob];
    float4 y1 = *(const float4*)&bt1[ob];
    float4 y2 = *(const float4*)&bt2[ob];
    const float sb[4] = {x1.x + x2.x, x1.y + x2.y, x1.z + x2.z, x1.w + x2.w};
    const float tb[4] = {y1.x + y2.x, y1.y + y2.y, y1.z + y2.z, y1.w + y2.w};
#pragma unroll
    for (int nr = 0; nr < 4; ++nr) {
      const int t = t0 + wn * 64 + nr * 16 + lr;
      float zv[4];
#pragma unroll
      for (int j = 0; j < 4; ++j) {
        float sv = accS[mr][nr][j] + sb[j];
        float tv = accT[mr][nr][j] + tb[j];
        float sg = __builtin_amdgcn_rcpf(1.f + __expf(-sv));
        float e2 = __expf(2.f * tv);
        float th = 1.f - 2.f * __builtin_amdgcn_rcpf(e2 + 1.f);
        zv[j] = sg * th;
      }
      *(uint2*)&z[((size_t)b * HROWS + t) * CCH + ob] = make_uint2(pk2(zv[0], zv[1]), pk2(zv[2], zv[3]));
    }
  }
}

// ---------------- update: [skip_w; res_w] @ z, RMW skip/out ----------------
template <int PRE>
__global__ __launch_bounds__(256, 2) void update_kernel(
    const hfu* __restrict__ z, const void* __restrict__ wp,
    const float* __restrict__ skwf, const float* __restrict__ rswf,
    const float* __restrict__ skb, const float* __restrict__ rsb,
    float* __restrict__ skip, float* __restrict__ outf, hfu* __restrict__ outb) {
  __shared__ uint4 sm[2048];  // 32KB
  uint4* sA = sm;
  uint4* sB = sm + 1024;
  const int tid = threadIdx.x;
  const int lane = tid & 63, wid = tid >> 6;
  const int wm = wid >> 1, wn = wid & 1;
  const int lr = lane & 15, lq = lane >> 4;
  const int t0 = blockIdx.x * BN;
  const int r0 = blockIdx.y * BM;  // 0..640
  const int b = blockIdx.z;

  f32x4 acc[4][4] = {};
  for (int kt = 0; kt < 8; ++kt) {
#pragma unroll
    for (int c = 0; c < 4; ++c) {
      const int cb = c * 256 + wid * 64;
      const int ch = cb + lane;
      const int ksub = ch >> 7, mn = ch & 127;
      const int k0 = kt * 64 + ksub * 8;
      if (PRE) {
        GLOAD16((const hfu*)wp + (size_t)(r0 + mn) * CCH + k0, &sA[cb]);
      } else {
        const int R = r0 + mn;
        const float* src = (R < SKP) ? (skwf + (size_t)R * CCH + k0)
                                     : (rswf + (size_t)(R - SKP) * CCH + k0);
        float4 f0 = *(const float4*)&src[0];
        float4 f1 = *(const float4*)&src[4];
        float v[8] = {f0.x, f0.y, f0.z, f0.w, f1.x, f1.y, f1.z, f1.w};
        sA[ch] = pk8(v);
      }
      GLOAD16(z + ((size_t)b * HROWS + t0 + mn) * CCH + k0, &sB[cb]);
    }
    __syncthreads();
#pragma unroll
    for (int ks = 0; ks < 2; ++ks) {
      const int kb = (ks * 4 + lq) * 128;
      half8 av[4], bv[4];
#pragma unroll
      for (int r = 0; r < 4; ++r) {
        av[r] = *(const half8*)&sA[kb + wm * 64 + r * 16 + lr];
        bv[r] = *(const half8*)&sB[kb + wn * 64 + r * 16 + lr];
      }
#pragma unroll
      for (int mr = 0; mr < 4; ++mr)
#pragma unroll
        for (int nr = 0; nr < 4; ++nr)
          acc[mr][nr] = __builtin_amdgcn_mfma_f32_16x16x32_f16(av[mr], bv[nr], acc[mr][nr], 0, 0, 0);
    }
    __syncthreads();
  }

  const bool iskip = (r0 < SKP);
#pragma unroll
  for (int mr = 0; mr < 4; ++mr) {
    const int R = r0 + wm * 64 + mr * 16 + lq * 4;
#pragma unroll
    for (int nr = 0; nr < 4; ++nr) {
      const int t = t0 + wn * 64 + nr * 16 + lr;
      if (t < T_LEN) {
        if (iskip) {
          float4 bb = *(const float4*)&skb[R];
          float4* p = (float4*)&skip[((size_t)b * T_LEN + t) * SKP + R];
          float4 v = *p;
          v.x += acc[mr][nr][0] + bb.x;
          v.y += acc[mr][nr][1] + bb.y;
          v.z += acc[mr][nr][2] + bb.z;
          v.w += acc[mr][nr][3] + bb.w;
          *p = v;
        } else {
          const int rr = R - SKP;
          float4 bb = *(const float4*)&rsb[rr];
          float4* p = (float4*)&outf[((size_t)b * ROWS + PADF + t) * CCH + rr];
          float4 v = *p;
          v.x += acc[mr][nr][0] + bb.x;
          v.y += acc[mr][nr][1] + bb.y;
          v.z += acc[mr][nr][2] + bb.z;
          v.w += acc[mr][nr][3] + bb.w;
          *p = v;
          if (PRE)
            *(uint2*)&outb[((size_t)b * ROWS + PADF + t) * CCH + rr] =
                make_uint2(pk2(v.x, v.y), pk2(v.z, v.w));
        }
      }
    }
  }
}

// ---------------- post1: y1 = relu(W1 @ relu(skip) + b1) -> fp16 ----------------
__global__ __launch_bounds__(256, 2) void post1_kernel(const float* __restrict__ skip,
                                                       const hfu* __restrict__ w,
                                                       const float* __restrict__ bias,
                                                       hfu* __restrict__ y1) {
  __shared__ uint4 sm[2048];
  uint4* sA = sm;
  uint4* sB = sm + 1024;
  const int tid = threadIdx.x;
  const int lane = tid & 63, wid = tid >> 6;
  const int wm = wid >> 1, wn = wid & 1;
  const int lr = lane & 15, lq = lane >> 4;
  const int t0 = blockIdx.x * BN;
  const int r0 = blockIdx.y * BM;
  const int b = blockIdx.z;
  f32x4 acc[4][4] = {};
  for (int kt = 0; kt < 4; ++kt) {  // K=256
#pragma unroll
    for (int c = 0; c < 4; ++c) {
      const int cb = c * 256 + wid * 64;
      const int ch = cb + lane;
      const int ksub = ch >> 7, mn = ch & 127;
      const int k0 = kt * 64 + ksub * 8;
      GLOAD16(w + (size_t)(r0 + mn) * SKP + k0, &sA[cb]);
      int row = t0 + mn;
      if (row > T_LEN - 1) row = T_LEN - 1;
      const float* src = skip + ((size_t)b * T_LEN + row) * SKP + k0;
      float4 f0 = *(const float4*)&src[0];
      float4 f1 = *(const float4*)&src[4];
      float v[8] = {fmaxf(f0.x, 0.f), fmaxf(f0.y, 0.f), fmaxf(f0.z, 0.f), fmaxf(f0.w, 0.f),
                    fmaxf(f1.x, 0.f), fmaxf(f1.y, 0.f), fmaxf(f1.z, 0.f), fmaxf(f1.w, 0.f)};
      sB[ch] = pk8(v);
    }
    __syncthreads();
#pragma unroll
    for (int ks = 0; ks < 2; ++ks) {
      const int kb = (ks * 4 + lq) * 128;
      half8 av[4], bv[4];
#pragma unroll
      for (int r = 0; r < 4; ++r) {
        av[r] = *(const half8*)&sA[kb + wm * 64 + r * 16 + lr];
        bv[r] = *(const half8*)&sB[kb + wn * 64 + r * 16 + lr];
      }
#pragma unroll
      for (int mr = 0; mr < 4; ++mr)
#pragma unroll
        for (int nr = 0; nr < 4; ++nr)
          acc[mr][nr] = __builtin_amdgcn_mfma_f32_16x16x32_f16(av[mr], bv[nr], acc[mr][nr], 0, 0, 0);
    }
    __syncthreads();
  }
#pragma unroll
  for (int mr = 0; mr < 4; ++mr) {
    const int ob = r0 + wm * 64 + mr * 16 + lq * 4;
    float4 bb = *(const float4*)&bias[ob];
    const float bs[4] = {bb.x, bb.y, bb.z, bb.w};
#pragma unroll
    for (int nr = 0; nr < 4; ++nr) {
      const int t = t0 + wn * 64 + nr * 16 + lr;
      float v[4];
#pragma unroll
      for (int j = 0; j < 4; ++j) v[j] = fmaxf(acc[mr][nr][j] + bs[j], 0.f);
      *(uint2*)&y1[((size_t)b * HROWS + t) * SKP + ob] = make_uint2(pk2(v[0], v[1]), pk2(v[2], v[3]));
    }
  }
}

// ---------------- post2: out = W2 @ y1 + b2 -> d_out [b][t][q] fp32 ----------------
__global__ __launch_bounds__(256, 2) void post2_kernel(const hfu* __restrict__ y1,
                                                       const hfu* __restrict__ w,
                                                       const float* __restrict__ bias,
                                                       float* __restrict__ outp) {
  __shared__ uint4 sm[2048];
  uint4* sA = sm;
  uint4* sB = sm + 1024;
  const int tid = threadIdx.x;
  const int lane = tid & 63, wid = tid >> 6;
  const int wm = wid >> 1, wn = wid & 1;
  const int lr = lane & 15, lq = lane >> 4;
  const int t0 = blockIdx.x * BN;
  const int r0 = blockIdx.y * BM;
  const int b = blockIdx.z;
  f32x4 acc[4][4] = {};
  for (int kt = 0; kt < 4; ++kt) {
#pragma unroll
    for (int c = 0; c < 4; ++c) {
      const int cb = c * 256 + wid * 64;
      const int ch = cb + lane;
      const int ksub = ch >> 7, mn = ch & 127;
      const int k0 = kt * 64 + ksub * 8;
      GLOAD16(w + (size_t)(r0 + mn) * SKP + k0, &sA[cb]);
      GLOAD16(y1 + ((size_t)b * HROWS + t0 + mn) * SKP + k0, &sB[cb]);
    }
    __syncthreads();
#pragma unroll
    for (int ks = 0; ks < 2; ++ks) {
      const int kb = (ks * 4 + lq) * 128;
      half8 av[4], bv[4];
#pragma unroll
      for (int r = 0; r < 4; ++r) {
        av[r] = *(const half8*)&sA[kb + wm * 64 + r * 16 + lr];
        bv[r] = *(const half8*)&sB[kb + wn * 64 + r * 16 + lr];
      }
#pragma unroll
      for (int mr = 0; mr < 4; ++mr)
#pragma unroll
        for (int nr = 0; nr < 4; ++nr)
          acc[mr][nr] = __builtin_amdgcn_mfma_f32_16x16x32_f16(av[mr], bv[nr], acc[mr][nr], 0, 0, 0);
    }
    __syncthreads();
  }
#pragma unroll
  for (int mr = 0; mr < 4; ++mr) {
    const int ob = r0 + wm * 64 + mr * 16 + lq * 4;
    float4 bb = *(const float4*)&bias[ob];
#pragma unroll
    for (int nr = 0; nr < 4; ++nr) {
      const int t = t0 + wn * 64 + nr * 16 + lr;
      if (t < T_LEN) {
        float4 v;
        v.x = acc[mr][nr][0] + bb.x;
        v.y = acc[mr][nr][1] + bb.y;
        v.z = acc[mr][nr][2] + bb.z;
        v.w = acc[mr][nr][3] + bb.w;
        *(float4*)&outp[((size_t)b * T_LEN + t) * NQ + ob] = v;
      }
    }
  }
}

extern "C" void kernel_launch(void* const* d_in, const int* in_sizes, int n_in,
                              void* d_out, int out_size, void* d_ws, size_t ws_size,
                              hipStream_t stream) {
  const int* x = (const int*)d_in[0];
  const float* h = (const float*)d_in[1];
  const float* causal_w = (const float*)d_in[2];
  const float* causal_b = (const float*)d_in[3];
  const float* dil_sig_w = (const float*)d_in[4];
  const float* dil_sig_b = (const float*)d_in[5];
  const float* dil_tanh_w = (const float*)d_in[6];
  const float* dil_tanh_b = (const float*)d_in[7];
  const float* aux_sig_w = (const float*)d_in[8];
  const float* aux_sig_b = (const float*)d_in[9];
  const float* aux_tanh_w = (const float*)d_in[10];
  const float* aux_tanh_b = (const float*)d_in[11];
  const float* skip_w = (const float*)d_in[12];
  const float* skip_b = (const float*)d_in[13];
  const float* res_w = (const float*)d_in[14];
  const float* res_b = (const float*)d_in[15];
  const float* post1_w = (const float*)d_in[16];
  const float* post1_b = (const float*)d_in[17];
  const float* post2_w = (const float*)d_in[18];
  const float* post2_b = (const float*)d_in[19];
  float* outp = (float*)d_out;

  char* p = (char*)d_ws;
  auto alloc = [&](size_t bytes) {
    char* r = p;
    p += (bytes + 255) & ~(size_t)255;
    return r;
  };
  float* outf = (float*)alloc((size_t)BATCH * ROWS * CCH * 4);   // padded fp32 residual master
  float* skip = (float*)alloc((size_t)BATCH * T_LEN * SKP * 4);  // fp32 skip accumulator
  hfu* zb = (hfu*)alloc((size_t)BATCH * HROWS * CCH * 2);        // z fp16 (reused as y1)
  hfu* hbf = (hfu*)alloc((size_t)BATCH * HROWS * AUXP * 2);
  hfu* auxsb = (hfu*)alloc((size_t)NLAYER * CCH * AUXP * 2);
  hfu* auxtb = (hfu*)alloc((size_t)NLAYER * CCH * AUXP * 2);
  hfu* p1b = (hfu*)alloc((size_t)NQ * SKP * 2);
  hfu* p2b = (hfu*)alloc((size_t)NQ * SKP * 2);
  hfu* y1 = zb;
  // optional (PRE) region
  hfu* outb = (hfu*)alloc((size_t)BATCH * ROWS * CCH * 2);
  hfu* dilS = (hfu*)alloc((size_t)NLAYER * 2 * CCH * CCH * 2);
  hfu* dilT = (hfu*)alloc((size_t)NLAYER * 2 * CCH * CCH * 2);
  hfu* wsr = (hfu*)alloc((size_t)NLAYER * 768 * CCH * 2);
  const bool pre = ((size_t)(p - (char*)d_ws) <= ws_size);

  // weight conversions
  cvt_aux<<<256, 256, 0, stream>>>(aux_sig_w, auxsb);
  cvt_aux<<<256, 256, 0, stream>>>(aux_tanh_w, auxtb);
  cvt_copy<<<64, 256, 0, stream>>>(post1_w, p1b, NQ * SKP);
  cvt_copy<<<64, 256, 0, stream>>>(post2_w, p2b, NQ * SKP);
  if (pre) {
    cvt_dil<<<2048, 256, 0, stream>>>(dil_sig_w, dilS);
    cvt_dil<<<2048, 256, 0, stream>>>(dil_tanh_w, dilT);
    cvt_skipres<<<2048, 256, 0, stream>>>(skip_w, res_w, wsr);
  }

  // zero: skip + padded rows of outf (and outb)
  zero16<<<512, 256, 0, stream>>>((uint4*)skip, (int)((size_t)BATCH * T_LEN * SKP * 4 / 16));
  for (int b = 0; b < BATCH; ++b) {
    zero16<<<64, 256, 0, stream>>>((uint4*)(outf + (size_t)b * ROWS * CCH), PADF * CCH * 4 / 16);
    zero16<<<16, 256, 0, stream>>>((uint4*)(outf + ((size_t)b * ROWS + PADF + T_LEN) * CCH), 64 * CCH * 4 / 16);
    if (pre) {
      zero16<<<32, 256, 0, stream>>>((uint4*)(outb + (size_t)b * ROWS * CCH), PADF * CCH * 2 / 16);
      zero16<<<8, 256, 0, stream>>>((uint4*)(outb + ((size_t)b * ROWS + PADF + T_LEN) * CCH), 64 * CCH * 2 / 16);
    }
  }

  htrans_kernel<<<dim3(126, 2), 256, 0, stream>>>(h, hbf);
  if (pre)
    embed_kernel<1><<<dim3(2000, 2), 256, 0, stream>>>(x, causal_w, causal_b, outf, outb);
  else
    embed_kernel<0><<<dim3(2000, 2), 256, 0, stream>>>(x, causal_w, causal_b, outf, nullptr);

  for (int l = 0; l < NLAYER; ++l) {
    const int d = 1 << (l % 10);
    if (pre) {
      gate_kernel<1><<<dim3(NTT, 4, BATCH), 256, 0, stream>>>(
          outb, outf, hbf, dilS + (size_t)l * 2 * CCH * CCH, dilT + (size_t)l * 2 * CCH * CCH,
          auxsb + (size_t)l * CCH * AUXP, auxtb + (size_t)l * CCH * AUXP,
          dil_sig_b + (size_t)l * CCH, aux_sig_b + (size_t)l * CCH,
          dil_tanh_b + (size_t)l * CCH, aux_tanh_b + (size_t)l * CCH, zb, d);
      update_kernel<1><<<dim3(NTT, 6, BATCH), 256, 0, stream>>>(
          zb, wsr + (size_t)l * 768 * CCH, nullptr, nullptr,
          skip_b + (size_t)l * SKP, res_b + (size_t)l * CCH, skip, outf, outb);
    } else {
      gate_kernel<0><<<dim3(NTT, 4, BATCH), 256, 0, stream>>>(
          nullptr, outf, hbf, dil_sig_w + (size_t)l * CCH * CCH * 2,
          dil_tanh_w + (size_t)l * CCH * CCH * 2,
          auxsb + (size_t)l * CCH * AUXP, auxtb + (size_t)l * CCH * AUXP,
          dil_sig_b + (size_t)l * CCH, aux_sig_b + (size_t)l * CCH,
          dil_tanh_b + (size_t)l * CCH, aux_tanh_b + (size_t)l * CCH, zb, d);
      update_kernel<0><<<dim3(NTT, 6, BATCH), 256, 0, stream>>>(
          zb, nullptr, skip_w + (size_t)l * SKP * CCH, res_w + (size_t)l * CCH * CCH,
          skip_b + (size_t)l * SKP, res_b + (size_t)l * CCH, skip, outf, nullptr);
    }
  }

  post1_kernel<<<dim3(NTT, 2, BATCH), 256, 0, stream>>>(skip, p1b, post1_b, y1);
  post2_kernel<<<dim3(NTT, 2, BATCH), 256, 0, stream>>>(y1, p2b, post2_b, outp);
}

// Round 4
// 3822.065 us; speedup vs baseline: 11.9414x; 1.0212x over previous
//
#include <hip/hip_runtime.h>
#include <math.h>

#define T_LEN 8000
#define BATCH 2
#define CCH 512
#define SKP 256
#define AUXP 32
#define NQ 256
#define NLAYER 30
#define PADF 512
#define ROWS (PADF + T_LEN + 64)   // 8576 padded rows (fp32 master / fp16 copy)
#define HROWS (T_LEN + 64)         // 8064 rows (z, h, y1)
#define BM 128
#define BN 128
#define NTT 63                     // ceil(8000/128)

typedef unsigned short hfu;        // fp16 as raw bits
typedef unsigned int u32;
typedef __attribute__((ext_vector_type(8))) _Float16 half8;
typedef __attribute__((ext_vector_type(4))) float f32x4;

#define GLOAD16(g, l)                                                          \
  __builtin_amdgcn_global_load_lds(                                            \
      (const __attribute__((address_space(1))) void*)(g),                      \
      (__attribute__((address_space(3))) void*)(l), 16, 0, 0)

__device__ inline hfu hfbits(float f) {
  union { _Float16 h; hfu u; } x;
  x.h = (_Float16)f;
  return x.u;
}
__device__ inline u32 pk2(float a, float b) {
  return (u32)hfbits(a) | ((u32)hfbits(b) << 16);
}
__device__ inline uint4 pk8(const float f[8]) {
  return make_uint4(pk2(f[0], f[1]), pk2(f[2], f[3]), pk2(f[4], f[5]), pk2(f[6], f[7]));
}

// ---------------- utility: zero / converts ----------------
__global__ __launch_bounds__(256) void zero16(uint4* p, int n) {
  for (int i = blockIdx.x * 256 + threadIdx.x; i < n; i += gridDim.x * 256)
    p[i] = make_uint4(0u, 0u, 0u, 0u);
}

// dil weights: in [30][512][512][2] f32 -> out [30][2][512][512] fp16 (tap-deinterleaved)
__global__ __launch_bounds__(256) void cvt_dil(const float* __restrict__ in, hfu* __restrict__ out) {
  const long NG = (long)NLAYER * CCH * (CCH / 4);
  for (long g = (long)blockIdx.x * 256 + threadIdx.x; g < NG; g += (long)gridDim.x * 256) {
    const int i4 = (int)(g & 127) * 4;
    const int o = (int)((g >> 7) & 511);
    const int l = (int)(g >> 16);
    const float* pp = in + (((size_t)l * CCH + o) * CCH + i4) * 2;
    float4 f0 = *(const float4*)pp;
    float4 f1 = *(const float4*)(pp + 4);
    uint2 t0 = make_uint2(pk2(f0.x, f0.z), pk2(f1.x, f1.z));
    uint2 t1 = make_uint2(pk2(f0.y, f0.w), pk2(f1.y, f1.w));
    hfu* ob = out + ((size_t)l * 2 * CCH + o) * CCH + i4;
    *(uint2*)ob = t0;
    *(uint2*)(ob + (size_t)CCH * CCH) = t1;
  }
}

// skip_w [30][256][512] + res_w [30][512][512] -> stacked [30][768][512] fp16
__global__ __launch_bounds__(256) void cvt_skipres(const float* __restrict__ skw,
                                                   const float* __restrict__ rsw,
                                                   hfu* __restrict__ out) {
  const long NG = (long)NLAYER * 768 * (CCH / 4);
  for (long g = (long)blockIdx.x * 256 + threadIdx.x; g < NG; g += (long)gridDim.x * 256) {
    const int i4 = (int)(g & 127) * 4;
    const int r = (int)((g >> 7) % 768);
    const int l = (int)(g / (128 * 768));
    const float* src = (r < SKP) ? (skw + ((size_t)l * SKP + r) * CCH + i4)
                                 : (rsw + ((size_t)l * CCH + (r - SKP)) * CCH + i4);
    float4 f = *(const float4*)src;
    *(uint2*)(out + ((size_t)l * 768 + r) * CCH + i4) = make_uint2(pk2(f.x, f.y), pk2(f.z, f.w));
  }
}

// aux weights [30][512][28] -> [30][512][32] fp16 zero-padded
__global__ __launch_bounds__(256) void cvt_aux(const float* __restrict__ in, hfu* __restrict__ out) {
  const int N = NLAYER * CCH * AUXP;
  for (int i = blockIdx.x * 256 + threadIdx.x; i < N; i += gridDim.x * 256) {
    const int j = i & 31;
    const int o = (i >> 5) & 511;
    const int l = i >> 14;
    float v = (j < 28) ? in[((size_t)l * CCH + o) * 28 + j] : 0.f;
    out[i] = hfbits(v);
  }
}

__global__ __launch_bounds__(256) void cvt_copy(const float* __restrict__ in, hfu* __restrict__ out, int n) {
  for (int i = blockIdx.x * 256 + threadIdx.x; i < n; i += gridDim.x * 256)
    out[i] = hfbits(in[i]);
}

// h [b][28][8000] f32 -> [b][8064][32] fp16 zero-padded
__global__ __launch_bounds__(256) void htrans_kernel(const float* __restrict__ h, hfu* __restrict__ hbf) {
  const int b = blockIdx.y;
  const int t = blockIdx.x * 64 + (threadIdx.x & 63);
  const int j0 = threadIdx.x >> 6;
#pragma unroll
  for (int j = j0; j < AUXP; j += 4) {
    float v = (j < 28 && t < T_LEN) ? h[((size_t)b * 28 + j) * T_LEN + t] : 0.f;
    hbf[((size_t)b * HROWS + t) * AUXP + j] = hfbits(v);
  }
}

// ---------------- embed ----------------
template <int PRE>
__global__ __launch_bounds__(256) void embed_kernel(const int* __restrict__ x,
                                                    const float* __restrict__ cw,
                                                    const float* __restrict__ cb,
                                                    float* __restrict__ outf,
                                                    hfu* __restrict__ outb) {
  const int b = blockIdx.y;
  const int t = blockIdx.x * 4 + (threadIdx.x >> 6);
  const int lane = threadIdx.x & 63;
  const int xc = x[(size_t)b * T_LEN + t] & 255;
  const int xp = (t > 0) ? (x[(size_t)b * T_LEN + t - 1] & 255) : 0;
#pragma unroll
  for (int j = 0; j < 8; ++j) {
    const int o = lane + j * 64;
    float v = cb[o] + cw[((size_t)o * NQ + xc) * 2 + 1];
    if (t > 0) v += cw[((size_t)o * NQ + xp) * 2];
    outf[((size_t)b * ROWS + PADF + t) * CCH + o] = v;
    if (PRE) outb[((size_t)b * ROWS + PADF + t) * CCH + o] = hfbits(v);
  }
}

// ---------------- gate: sig/tanh dilated GEMMs + aux + gating ----------------
// 2-phase double-buffered staging (BK=32 halves); XCD-chunked block mapping:
// grid=504 1D; xcd = n&7 owns one (o0 group, batch) and all 63 t-tiles so the
// weight slice (512KB) stays hot in that XCD's L2.
template <int PRE>
__global__ __launch_bounds__(256, 2) void gate_kernel(
    const hfu* __restrict__ actb, const float* __restrict__ actf,
    const hfu* __restrict__ hbf,
    const void* __restrict__ wsp, const void* __restrict__ wtp,
    const hfu* __restrict__ auxs, const hfu* __restrict__ auxt,
    const float* __restrict__ bs1, const float* __restrict__ bs2,
    const float* __restrict__ bt1, const float* __restrict__ bt2,
    hfu* __restrict__ z, int d) {
  // 48KB: 2 phases x {As[4][128][8], At[4][128][8], B[4][128][8]} fp16
  __shared__ uint4 sm[3072];
  const int tid = threadIdx.x;
  const int lane = tid & 63, wid = tid >> 6;
  const int wm = wid >> 1, wn = wid & 1;
  const int lr = lane & 15, lq = lane >> 4;

  const int n = blockIdx.x;          // 0..503 = 8 xcd * 63 slot
  const int xcd = n & 7, slot = n >> 3;
  const int o0 = (xcd >> 1) * BM;    // o0 group per XCD pair
  const int b = xcd & 1;
  const int t0 = slot * BN;

  f32x4 accS[4][4] = {};
  f32x4 accT[4][4] = {};

  // stage one BK=32 half (ih in [0,32): ih<16 -> tau=1, else tau=0)
  auto stage_half = [&](int ih, int p) {
    const int tau = (ih < 16) ? 1 : 0;
    const int koff = (ih & 15) * 32;
    const int base = p * 1536;
#pragma unroll
    for (int c = 0; c < 2; ++c) {
      const int cb = c * 256 + wid * 64;
      const int ch = cb + lane;
      const int ksub = ch >> 7, mn = ch & 127;
      const int i0 = koff + ksub * 8;
      if (PRE) {
        const hfu* ws = (const hfu*)wsp + ((size_t)tau * CCH + o0 + mn) * CCH + i0;
        const hfu* wt = (const hfu*)wtp + ((size_t)tau * CCH + o0 + mn) * CCH + i0;
        GLOAD16(ws, &sm[base + cb]);
        GLOAD16(wt, &sm[base + 512 + cb]);
        const hfu* ar = actb + ((size_t)b * ROWS + PADF + t0 + mn - (tau ? 0 : d)) * CCH + i0;
        GLOAD16(ar, &sm[base + 1024 + cb]);
      } else {
        const float* wsf = (const float*)wsp;
        const float* wtf = (const float*)wtp;
        const size_t fb = ((size_t)(o0 + mn) * CCH + i0) * 2;
        float vs[8], vt[8];
#pragma unroll
        for (int j = 0; j < 4; ++j) {
          float4 fs = *(const float4*)&wsf[fb + j * 4];
          float4 ft = *(const float4*)&wtf[fb + j * 4];
          vs[2 * j] = tau ? fs.y : fs.x;
          vs[2 * j + 1] = tau ? fs.w : fs.z;
          vt[2 * j] = tau ? ft.y : ft.x;
          vt[2 * j + 1] = tau ? ft.w : ft.z;
        }
        sm[base + ch] = pk8(vs);
        sm[base + 512 + ch] = pk8(vt);
        const float* ar = actf + ((size_t)b * ROWS + PADF + t0 + mn - (tau ? 0 : d)) * CCH + i0;
        float4 f0 = *(const float4*)&ar[0];
        float4 f1 = *(const float4*)&ar[4];
        float vb[8] = {f0.x, f0.y, f0.z, f0.w, f1.x, f1.y, f1.z, f1.w};
        sm[base + 1024 + ch] = pk8(vb);
      }
    }
  };

  // stage aux tiles (K=32, padded 28) into phase p
  auto stage_aux = [&](int p) {
    const int base = p * 1536;
#pragma unroll
    for (int c = 0; c < 2; ++c) {
      const int cb = c * 256 + wid * 64;
      const int ch = cb + lane;
      const int ksub = ch >> 7, mn = ch & 127;
      GLOAD16(auxs + (size_t)(o0 + mn) * AUXP + ksub * 8, &sm[base + cb]);
      GLOAD16(auxt + (size_t)(o0 + mn) * AUXP + ksub * 8, &sm[base + 512 + cb]);
      GLOAD16(hbf + ((size_t)b * HROWS + t0 + mn) * AUXP + ksub * 8, &sm[base + 1024 + cb]);
    }
  };

  // compute one K=32 half from phase p: 32 MFMAs/wave
  auto compute_half = [&](int p) {
    const int base = p * 1536;
    const int kb = lq * 128;
    half8 af[4], ag[4], bv[4];
#pragma unroll
    for (int r = 0; r < 4; ++r) {
      af[r] = *(const half8*)&sm[base + kb + wm * 64 + r * 16 + lr];
      ag[r] = *(const half8*)&sm[base + 512 + kb + wm * 64 + r * 16 + lr];
      bv[r] = *(const half8*)&sm[base + 1024 + kb + wn * 64 + r * 16 + lr];
    }
#pragma unroll
    for (int mr = 0; mr < 4; ++mr)
#pragma unroll
      for (int nr = 0; nr < 4; ++nr) {
        accS[mr][nr] = __builtin_amdgcn_mfma_f32_16x16x32_f16(af[mr], bv[nr], accS[mr][nr], 0, 0, 0);
        accT[mr][nr] = __builtin_amdgcn_mfma_f32_16x16x32_f16(ag[mr], bv[nr], accT[mr][nr], 0, 0, 0);
      }
  };

  stage_half(0, 0);
  __syncthreads();
  for (int ih = 0; ih < 32; ++ih) {
    const int pn = (ih + 1) & 1;
    if (ih < 31)
      stage_half(ih + 1, pn);   // prefetch next half into alternate phase
    else
      stage_aux(pn);            // virtual half 32 = aux (phase 0)
    compute_half(ih & 1);
    __syncthreads();
  }
  compute_half(0);              // aux

  // epilogue: bias + sigmoid*tanh -> z fp16 [b][t][ch]
#pragma unroll
  for (int mr = 0; mr < 4; ++mr) {
    const int ob = o0 + wm * 64 + mr * 16 + lq * 4;
    float4 x1 = *(const float4*)&bs1[ob];
    float4 x2 = *(const float4*)&bs2[ob];
    float4 y1 = *(const float4*)&bt1[ob];
    float4 y2 = *(const float4*)&bt2[ob];
    const float sb[4] = {x1.x + x2.x, x1.y + x2.y, x1.z + x2.z, x1.w + x2.w};
    const float tb[4] = {y1.x + y2.x, y1.y + y2.y, y1.z + y2.z, y1.w + y2.w};
#pragma unroll
    for (int nr = 0; nr < 4; ++nr) {
      const int t = t0 + wn * 64 + nr * 16 + lr;
      float zv[4];
#pragma unroll
      for (int j = 0; j < 4; ++j) {
        float sv = accS[mr][nr][j] + sb[j];
        float tv = accT[mr][nr][j] + tb[j];
        float sg = __builtin_amdgcn_rcpf(1.f + __expf(-sv));
        float e2 = __expf(2.f * tv);
        float th = 1.f - 2.f * __builtin_amdgcn_rcpf(e2 + 1.f);
        zv[j] = sg * th;
      }
      *(uint2*)&z[((size_t)b * HROWS + t) * CCH + ob] = make_uint2(pk2(zv[0], zv[1]), pk2(zv[2], zv[3]));
    }
  }
}

// ---------------- update: [skip_w; res_w] @ z, RMW skip/out ----------------
// 2-phase double-buffered; bijective chunked XCD mapping (m204) so each XCD's
// resident blocks share <=2 weight row-groups (<=256KB) in its L2.
template <int PRE>
__global__ __launch_bounds__(256, 2) void update_kernel(
    const hfu* __restrict__ z, const void* __restrict__ wp,
    const float* __restrict__ skwf, const float* __restrict__ rswf,
    const float* __restrict__ skb, const float* __restrict__ rsb,
    float* __restrict__ skip, float* __restrict__ outf, hfu* __restrict__ outb) {
  // 32KB: 2 phases x {A[4][128][8], B[4][128][8]} fp16
  __shared__ uint4 sm[2048];
  const int tid = threadIdx.x;
  const int lane = tid & 63, wid = tid >> 6;
  const int wm = wid >> 1, wn = wid & 1;
  const int lr = lane & 15, lq = lane >> 4;

  // bijective chunk: 756 blocks -> xcd = n&7 gets contiguous flat range
  const int n = blockIdx.x;
  const int xcd = n & 7, j = n >> 3;
  const int f = (xcd < 4) ? xcd * 95 + j : 380 + (xcd - 4) * 94 + j;
  const int rg = f / 126, tb = f - rg * 126;
  const int b = tb & 1, tt = tb >> 1;
  const int r0 = rg * BM;   // 0..640
  const int t0 = tt * BN;

  f32x4 acc[4][4] = {};

  auto stage_u = [&](int ihh, int p) {
    const int base = p * 1024;
#pragma unroll
    for (int c = 0; c < 2; ++c) {
      const int cb = c * 256 + wid * 64;
      const int ch = cb + lane;
      const int ksub = ch >> 7, mn = ch & 127;
      const int k0 = ihh * 32 + ksub * 8;
      if (PRE) {
        GLOAD16((const hfu*)wp + (size_t)(r0 + mn) * CCH + k0, &sm[base + cb]);
      } else {
        const int R = r0 + mn;
        const float* src = (R < SKP) ? (skwf + (size_t)R * CCH + k0)
                                     : (rswf + (size_t)(R - SKP) * CCH + k0);
        float4 f0 = *(const float4*)&src[0];
        float4 f1 = *(const float4*)&src[4];
        float v[8] = {f0.x, f0.y, f0.z, f0.w, f1.x, f1.y, f1.z, f1.w};
        sm[base + ch] = pk8(v);
      }
      GLOAD16(z + ((size_t)b * HROWS + t0 + mn) * CCH + k0, &sm[base + 512 + cb]);
    }
  };

  auto compute_u = [&](int p) {
    const int base = p * 1024;
    const int kb = lq * 128;
    half8 av[4], bv[4];
#pragma unroll
    for (int r = 0; r < 4; ++r) {
      av[r] = *(const half8*)&sm[base + kb + wm * 64 + r * 16 + lr];
      bv[r] = *(const half8*)&sm[base + 512 + kb + wn * 64 + r * 16 + lr];
    }
#pragma unroll
    for (int mr = 0; mr < 4; ++mr)
#pragma unroll
      for (int nr = 0; nr < 4; ++nr)
        acc[mr][nr] = __builtin_amdgcn_mfma_f32_16x16x32_f16(av[mr], bv[nr], acc[mr][nr], 0, 0, 0);
  };

  stage_u(0, 0);
  __syncthreads();
  for (int ihh = 0; ihh < 16; ++ihh) {
    if (ihh < 15) stage_u(ihh + 1, (ihh + 1) & 1);
    compute_u(ihh & 1);
    __syncthreads();
  }

  const bool iskip = (r0 < SKP);
#pragma unroll
  for (int mr = 0; mr < 4; ++mr) {
    const int R = r0 + wm * 64 + mr * 16 + lq * 4;
#pragma unroll
    for (int nr = 0; nr < 4; ++nr) {
      const int t = t0 + wn * 64 + nr * 16 + lr;
      if (t < T_LEN) {
        if (iskip) {
          float4 bb = *(const float4*)&skb[R];
          float4* p = (float4*)&skip[((size_t)b * T_LEN + t) * SKP + R];
          float4 v = *p;
          v.x += acc[mr][nr][0] + bb.x;
          v.y += acc[mr][nr][1] + bb.y;
          v.z += acc[mr][nr][2] + bb.z;
          v.w += acc[mr][nr][3] + bb.w;
          *p = v;
        } else {
          const int rr = R - SKP;
          float4 bb = *(const float4*)&rsb[rr];
          float4* p = (float4*)&outf[((size_t)b * ROWS + PADF + t) * CCH + rr];
          float4 v = *p;
          v.x += acc[mr][nr][0] + bb.x;
          v.y += acc[mr][nr][1] + bb.y;
          v.z += acc[mr][nr][2] + bb.z;
          v.w += acc[mr][nr][3] + bb.w;
          *p = v;
          if (PRE)
            *(uint2*)&outb[((size_t)b * ROWS + PADF + t) * CCH + rr] =
                make_uint2(pk2(v.x, v.y), pk2(v.z, v.w));
        }
      }
    }
  }
}

// ---------------- post1: y1 = relu(W1 @ relu(skip) + b1) -> fp16 ----------------
__global__ __launch_bounds__(256, 2) void post1_kernel(const float* __restrict__ skip,
                                                       const hfu* __restrict__ w,
                                                       const float* __restrict__ bias,
                                                       hfu* __restrict__ y1) {
  __shared__ uint4 sm[2048];
  uint4* sA = sm;
  uint4* sB = sm + 1024;
  const int tid = threadIdx.x;
  const int lane = tid & 63, wid = tid >> 6;
  const int wm = wid >> 1, wn = wid & 1;
  const int lr = lane & 15, lq = lane >> 4;
  const int t0 = blockIdx.x * BN;
  const int r0 = blockIdx.y * BM;
  const int b = blockIdx.z;
  f32x4 acc[4][4] = {};
  for (int kt = 0; kt < 4; ++kt) {  // K=256
#pragma unroll
    for (int c = 0; c < 4; ++c) {
      const int cb = c * 256 + wid * 64;
      const int ch = cb + lane;
      const int ksub = ch >> 7, mn = ch & 127;
      const int k0 = kt * 64 + ksub * 8;
      GLOAD16(w + (size_t)(r0 + mn) * SKP + k0, &sA[cb]);
      int row = t0 + mn;
      if (row > T_LEN - 1) row = T_LEN - 1;
      const float* src = skip + ((size_t)b * T_LEN + row) * SKP + k0;
      float4 f0 = *(const float4*)&src[0];
      float4 f1 = *(const float4*)&src[4];
      float v[8] = {fmaxf(f0.x, 0.f), fmaxf(f0.y, 0.f), fmaxf(f0.z, 0.f), fmaxf(f0.w, 0.f),
                    fmaxf(f1.x, 0.f), fmaxf(f1.y, 0.f), fmaxf(f1.z, 0.f), fmaxf(f1.w, 0.f)};
      sB[ch] = pk8(v);
    }
    __syncthreads();
#pragma unroll
    for (int ks = 0; ks < 2; ++ks) {
      const int kb = (ks * 4 + lq) * 128;
      half8 av[4], bv[4];
#pragma unroll
      for (int r = 0; r < 4; ++r) {
        av[r] = *(const half8*)&sA[kb + wm * 64 + r * 16 + lr];
        bv[r] = *(const half8*)&sB[kb + wn * 64 + r * 16 + lr];
      }
#pragma unroll
      for (int mr = 0; mr < 4; ++mr)
#pragma unroll
        for (int nr = 0; nr < 4; ++nr)
          acc[mr][nr] = __builtin_amdgcn_mfma_f32_16x16x32_f16(av[mr], bv[nr], acc[mr][nr], 0, 0, 0);
    }
    __syncthreads();
  }
#pragma unroll
  for (int mr = 0; mr < 4; ++mr) {
    const int ob = r0 + wm * 64 + mr * 16 + lq * 4;
    float4 bb = *(const float4*)&bias[ob];
    const float bs[4] = {bb.x, bb.y, bb.z, bb.w};
#pragma unroll
    for (int nr = 0; nr < 4; ++nr) {
      const int t = t0 + wn * 64 + nr * 16 + lr;
      float v[4];
#pragma unroll
      for (int j = 0; j < 4; ++j) v[j] = fmaxf(acc[mr][nr][j] + bs[j], 0.f);
      *(uint2*)&y1[((size_t)b * HROWS + t) * SKP + ob] = make_uint2(pk2(v[0], v[1]), pk2(v[2], v[3]));
    }
  }
}

// ---------------- post2: out = W2 @ y1 + b2 -> d_out [b][t][q] fp32 ----------------
__global__ __launch_bounds__(256, 2) void post2_kernel(const hfu* __restrict__ y1,
                                                       const hfu* __restrict__ w,
                                                       const float* __restrict__ bias,
                                                       float* __restrict__ outp) {
  __shared__ uint4 sm[2048];
  uint4* sA = sm;
  uint4* sB = sm + 1024;
  const int tid = threadIdx.x;
  const int lane = tid & 63, wid = tid >> 6;
  const int wm = wid >> 1, wn = wid & 1;
  const int lr = lane & 15, lq = lane >> 4;
  const int t0 = blockIdx.x * BN;
  const int r0 = blockIdx.y * BM;
  const int b = blockIdx.z;
  f32x4 acc[4][4] = {};
  for (int kt = 0; kt < 4; ++kt) {
#pragma unroll
    for (int c = 0; c < 4; ++c) {
      const int cb = c * 256 + wid * 64;
      const int ch = cb + lane;
      const int ksub = ch >> 7, mn = ch & 127;
      const int k0 = kt * 64 + ksub * 8;
      GLOAD16(w + (size_t)(r0 + mn) * SKP + k0, &sA[cb]);
      GLOAD16(y1 + ((size_t)b * HROWS + t0 + mn) * SKP + k0, &sB[cb]);
    }
    __syncthreads();
#pragma unroll
    for (int ks = 0; ks < 2; ++ks) {
      const int kb = (ks * 4 + lq) * 128;
      half8 av[4], bv[4];
#pragma unroll
      for (int r = 0; r < 4; ++r) {
        av[r] = *(const half8*)&sA[kb + wm * 64 + r * 16 + lr];
        bv[r] = *(const half8*)&sB[kb + wn * 64 + r * 16 + lr];
      }
#pragma unroll
      for (int mr = 0; mr < 4; ++mr)
#pragma unroll
        for (int nr = 0; nr < 4; ++nr)
          acc[mr][nr] = __builtin_amdgcn_mfma_f32_16x16x32_f16(av[mr], bv[nr], acc[mr][nr], 0, 0, 0);
    }
    __syncthreads();
  }
#pragma unroll
  for (int mr = 0; mr < 4; ++mr) {
    const int ob = r0 + wm * 64 + mr * 16 + lq * 4;
    float4 bb = *(const float4*)&bias[ob];
#pragma unroll
    for (int nr = 0; nr < 4; ++nr) {
      const int t = t0 + wn * 64 + nr * 16 + lr;
      if (t < T_LEN) {
        float4 v;
        v.x = acc[mr][nr][0] + bb.x;
        v.y = acc[mr][nr][1] + bb.y;
        v.z = acc[mr][nr][2] + bb.z;
        v.w = acc[mr][nr][3] + bb.w;
        *(float4*)&outp[((size_t)b * T_LEN + t) * NQ + ob] = v;
      }
    }
  }
}

extern "C" void kernel_launch(void* const* d_in, const int* in_sizes, int n_in,
                              void* d_out, int out_size, void* d_ws, size_t ws_size,
                              hipStream_t stream) {
  const int* x = (const int*)d_in[0];
  const float* h = (const float*)d_in[1];
  const float* causal_w = (const float*)d_in[2];
  const float* causal_b = (const float*)d_in[3];
  const float* dil_sig_w = (const float*)d_in[4];
  const float* dil_sig_b = (const float*)d_in[5];
  const float* dil_tanh_w = (const float*)d_in[6];
  const float* dil_tanh_b = (const float*)d_in[7];
  const float* aux_sig_w = (const float*)d_in[8];
  const float* aux_sig_b = (const float*)d_in[9];
  const float* aux_tanh_w = (const float*)d_in[10];
  const float* aux_tanh_b = (const float*)d_in[11];
  const float* skip_w = (const float*)d_in[12];
  const float* skip_b = (const float*)d_in[13];
  const float* res_w = (const float*)d_in[14];
  const float* res_b = (const float*)d_in[15];
  const float* post1_w = (const float*)d_in[16];
  const float* post1_b = (const float*)d_in[17];
  const float* post2_w = (const float*)d_in[18];
  const float* post2_b = (const float*)d_in[19];
  float* outp = (float*)d_out;

  char* p = (char*)d_ws;
  auto alloc = [&](size_t bytes) {
    char* r = p;
    p += (bytes + 255) & ~(size_t)255;
    return r;
  };
  float* outf = (float*)alloc((size_t)BATCH * ROWS * CCH * 4);   // padded fp32 residual master
  float* skip = (float*)alloc((size_t)BATCH * T_LEN * SKP * 4);  // fp32 skip accumulator
  hfu* zb = (hfu*)alloc((size_t)BATCH * HROWS * CCH * 2);        // z fp16 (reused as y1)
  hfu* hbf = (hfu*)alloc((size_t)BATCH * HROWS * AUXP * 2);
  hfu* auxsb = (hfu*)alloc((size_t)NLAYER * CCH * AUXP * 2);
  hfu* auxtb = (hfu*)alloc((size_t)NLAYER * CCH * AUXP * 2);
  hfu* p1b = (hfu*)alloc((size_t)NQ * SKP * 2);
  hfu* p2b = (hfu*)alloc((size_t)NQ * SKP * 2);
  hfu* y1 = zb;
  // optional (PRE) region
  hfu* outb = (hfu*)alloc((size_t)BATCH * ROWS * CCH * 2);
  hfu* dilS = (hfu*)alloc((size_t)NLAYER * 2 * CCH * CCH * 2);
  hfu* dilT = (hfu*)alloc((size_t)NLAYER * 2 * CCH * CCH * 2);
  hfu* wsr = (hfu*)alloc((size_t)NLAYER * 768 * CCH * 2);
  const bool pre = ((size_t)(p - (char*)d_ws) <= ws_size);

  // weight conversions
  cvt_aux<<<256, 256, 0, stream>>>(aux_sig_w, auxsb);
  cvt_aux<<<256, 256, 0, stream>>>(aux_tanh_w, auxtb);
  cvt_copy<<<64, 256, 0, stream>>>(post1_w, p1b, NQ * SKP);
  cvt_copy<<<64, 256, 0, stream>>>(post2_w, p2b, NQ * SKP);
  if (pre) {
    cvt_dil<<<2048, 256, 0, stream>>>(dil_sig_w, dilS);
    cvt_dil<<<2048, 256, 0, stream>>>(dil_tanh_w, dilT);
    cvt_skipres<<<2048, 256, 0, stream>>>(skip_w, res_w, wsr);
  }

  // zero: skip + padded rows of outf (and outb)
  zero16<<<512, 256, 0, stream>>>((uint4*)skip, (int)((size_t)BATCH * T_LEN * SKP * 4 / 16));
  for (int b = 0; b < BATCH; ++b) {
    zero16<<<64, 256, 0, stream>>>((uint4*)(outf + (size_t)b * ROWS * CCH), PADF * CCH * 4 / 16);
    zero16<<<16, 256, 0, stream>>>((uint4*)(outf + ((size_t)b * ROWS + PADF + T_LEN) * CCH), 64 * CCH * 4 / 16);
    if (pre) {
      zero16<<<32, 256, 0, stream>>>((uint4*)(outb + (size_t)b * ROWS * CCH), PADF * CCH * 2 / 16);
      zero16<<<8, 256, 0, stream>>>((uint4*)(outb + ((size_t)b * ROWS + PADF + T_LEN) * CCH), 64 * CCH * 2 / 16);
    }
  }

  htrans_kernel<<<dim3(126, 2), 256, 0, stream>>>(h, hbf);
  if (pre)
    embed_kernel<1><<<dim3(2000, 2), 256, 0, stream>>>(x, causal_w, causal_b, outf, outb);
  else
    embed_kernel<0><<<dim3(2000, 2), 256, 0, stream>>>(x, causal_w, causal_b, outf, nullptr);

  for (int l = 0; l < NLAYER; ++l) {
    const int d = 1 << (l % 10);
    if (pre) {
      gate_kernel<1><<<504, 256, 0, stream>>>(
          outb, outf, hbf, dilS + (size_t)l * 2 * CCH * CCH, dilT + (size_t)l * 2 * CCH * CCH,
          auxsb + (size_t)l * CCH * AUXP, auxtb + (size_t)l * CCH * AUXP,
          dil_sig_b + (size_t)l * CCH, aux_sig_b + (size_t)l * CCH,
          dil_tanh_b + (size_t)l * CCH, aux_tanh_b + (size_t)l * CCH, zb, d);
      update_kernel<1><<<756, 256, 0, stream>>>(
          zb, wsr + (size_t)l * 768 * CCH, nullptr, nullptr,
          skip_b + (size_t)l * SKP, res_b + (size_t)l * CCH, skip, outf, outb);
    } else {
      gate_kernel<0><<<504, 256, 0, stream>>>(
          nullptr, outf, hbf, dil_sig_w + (size_t)l * CCH * CCH * 2,
          dil_tanh_w + (size_t)l * CCH * CCH * 2,
          auxsb + (size_t)l * CCH * AUXP, auxtb + (size_t)l * CCH * AUXP,
          dil_sig_b + (size_t)l * CCH, aux_sig_b + (size_t)l * CCH,
          dil_tanh_b + (size_t)l * CCH, aux_tanh_b + (size_t)l * CCH, zb, d);
      update_kernel<0><<<756, 256, 0, stream>>>(
          zb, nullptr, skip_w + (size_t)l * SKP * CCH, res_w + (size_t)l * CCH * CCH,
          skip_b + (size_t)l * SKP, res_b + (size_t)l * CCH, skip, outf, nullptr);
    }
  }

  post1_kernel<<<dim3(NTT, 2, BATCH), 256, 0, stream>>>(skip, p1b, post1_b, y1);
  post2_kernel<<<dim3(NTT, 2, BATCH), 256, 0, stream>>>(y1, p2b, post2_b, outp);
}